// Round 4
// baseline (270.712 us; speedup 1.0000x reference)
//
#include <hip/hip_runtime.h>

#define NB 32
#define NN 256
#define DD 64
#define FMAXV 3.402823466e+38f

// R4: 1024 threads/block, 1 block per batch. thread = (node n = t&255,
// dim-slice s = t>>8, 16 dims each). 4 waves/SIMD (vs R3's 1) to hide
// scalar-load/LDS latency — R3 was latency-bound (VALUBusy 1.7% of a 12.5%
// ceiling at 1 wave/SIMD). Per-thread regs: h[64] + 16 accum + temps ~ 110,
// under the 128 cap imposed by __launch_bounds__(1024,4).
// readfirstlane(t>>8) pins the slice index to an SGPR so weight loads stay
// scalar. LDS staging stride 65 -> 2-way bank aliasing only (free).
__global__ __launch_bounds__(1024, 4) void pnet_kernel(
    const float* __restrict__ x,
    const float* __restrict__ W1,  const float* __restrict__ b1,
    const float* __restrict__ g1,  const float* __restrict__ beta1,
    const float* __restrict__ We1, const float* __restrict__ be1,
    const float* __restrict__ ge1, const float* __restrict__ bte1,
    const float* __restrict__ We2, const float* __restrict__ be2,
    const float* __restrict__ ge2, const float* __restrict__ bte2,
    const float* __restrict__ Wg1, const float* __restrict__ bg1,
    const float* __restrict__ Wg2, const float* __restrict__ bg2,
    float* __restrict__ out)
{
    __shared__ float T[NN * 65];      // 66.6 KB node x dim staging
    __shared__ float PA[16 * 64];     // partials (max / sum)
    __shared__ float PB[16 * 64];     // partials (min / max)
    __shared__ float redmax[DD], redmin[DD];
    __shared__ float xg[2 * DD];
    __shared__ float hid[DD];

    const int t  = threadIdx.x;
    const int b  = blockIdx.x;
    const int n  = t & 255;                                  // node
    const int s  = __builtin_amdgcn_readfirstlane(t >> 8);   // dim slice 0..3 (SGPR)
    const int rd = t & 63;                                   // reduce phase: dim
    const int rg = t >> 6;                                   // reduce phase: node group 0..15

    // ---------------- layer 1: h = bn(relu(x @ W1 + b1)), full 64 dims ----------------
    float4 xv = *(const float4*)(x + ((size_t)b * NN + n) * 4);
    float h[DD];
#pragma unroll
    for (int i = 0; i < 16; ++i) {
        float4 a  = ((const float4*)b1)[i];
        float4 w0 = ((const float4*)W1)[0 * 16 + i];
        float4 w1 = ((const float4*)W1)[1 * 16 + i];
        float4 w2 = ((const float4*)W1)[2 * 16 + i];
        float4 w3 = ((const float4*)W1)[3 * 16 + i];
        a.x += xv.x * w0.x + xv.y * w1.x + xv.z * w2.x + xv.w * w3.x;
        a.y += xv.x * w0.y + xv.y * w1.y + xv.z * w2.y + xv.w * w3.y;
        a.z += xv.x * w0.z + xv.y * w1.z + xv.z * w2.z + xv.w * w3.z;
        a.w += xv.x * w0.w + xv.y * w1.w + xv.z * w2.w + xv.w * w3.w;
        float4 g  = ((const float4*)g1)[i];
        float4 bt = ((const float4*)beta1)[i];
        h[4 * i + 0] = g.x * fmaxf(a.x, 0.f) + bt.x;
        h[4 * i + 1] = g.y * fmaxf(a.y, 0.f) + bt.y;
        h[4 * i + 2] = g.z * fmaxf(a.z, 0.f) + bt.z;
        h[4 * i + 3] = g.w * fmaxf(a.w, 0.f) + bt.w;
    }

    // ---------------- edge conv: computes this thread's 16 dims into hn ----------------
    auto edge_conv = [&](const float* __restrict__ We, const float* __restrict__ be,
                         const float* __restrict__ ge, const float* __restrict__ bte,
                         float* __restrict__ hn) {
        // ---- pass A: tj slice (weight rows 64..127, cols s*16..s*16+16) ----
        float4 a0 = make_float4(0.f,0.f,0.f,0.f), a1 = a0, a2 = a0, a3 = a0;
#pragma unroll
        for (int k = 0; k < DD; ++k) {
            const float hk = h[k];
            const float4* w = (const float4*)(We + (DD + k) * DD + s * 16);
            float4 w0 = w[0], w1 = w[1], w2 = w[2], w3 = w[3];
            a0.x = fmaf(hk, w0.x, a0.x); a0.y = fmaf(hk, w0.y, a0.y);
            a0.z = fmaf(hk, w0.z, a0.z); a0.w = fmaf(hk, w0.w, a0.w);
            a1.x = fmaf(hk, w1.x, a1.x); a1.y = fmaf(hk, w1.y, a1.y);
            a1.z = fmaf(hk, w1.z, a1.z); a1.w = fmaf(hk, w1.w, a1.w);
            a2.x = fmaf(hk, w2.x, a2.x); a2.y = fmaf(hk, w2.y, a2.y);
            a2.z = fmaf(hk, w2.z, a2.z); a2.w = fmaf(hk, w2.w, a2.w);
            a3.x = fmaf(hk, w3.x, a3.x); a3.y = fmaf(hk, w3.y, a3.y);
            a3.z = fmaf(hk, w3.z, a3.z); a3.w = fmaf(hk, w3.w, a3.w);
        }
        __syncthreads();                    // T free (prior readers done)
        {
            float* Tw = T + n * 65 + s * 16;
            Tw[ 0] = a0.x; Tw[ 1] = a0.y; Tw[ 2] = a0.z; Tw[ 3] = a0.w;
            Tw[ 4] = a1.x; Tw[ 5] = a1.y; Tw[ 6] = a1.z; Tw[ 7] = a1.w;
            Tw[ 8] = a2.x; Tw[ 9] = a2.y; Tw[10] = a2.z; Tw[11] = a2.w;
            Tw[12] = a3.x; Tw[13] = a3.y; Tw[14] = a3.z; Tw[15] = a3.w;
        }
        __syncthreads();
        // per-dim max/min over this group's 16 nodes
        {
            float mx = -FMAXV, mn = FMAXV;
#pragma unroll
            for (int m = 0; m < 16; ++m) {
                float v = T[(rg * 16 + m) * 65 + rd];
                mx = fmaxf(mx, v);
                mn = fminf(mn, v);
            }
            PA[rg * 64 + rd] = mx;
            PB[rg * 64 + rd] = mn;
        }
        __syncthreads();
        if (t < 64) {
            float amax = PA[t], amin = PB[t];
#pragma unroll
            for (int q = 1; q < 16; ++q) {
                amax = fmaxf(amax, PA[q * 64 + t]);
                amin = fminf(amin, PB[q * 64 + t]);
            }
            redmax[t] = amax;
            redmin[t] = amin;
        }
        __syncthreads();

        // ---- pass B: ti slice (weight rows 0..63) ----
        float4 c0 = make_float4(0.f,0.f,0.f,0.f), c1 = c0, c2 = c0, c3 = c0;
#pragma unroll
        for (int k = 0; k < DD; ++k) {
            const float hk = h[k];
            const float4* w = (const float4*)(We + k * DD + s * 16);
            float4 w0 = w[0], w1 = w[1], w2 = w[2], w3 = w[3];
            c0.x = fmaf(hk, w0.x, c0.x); c0.y = fmaf(hk, w0.y, c0.y);
            c0.z = fmaf(hk, w0.z, c0.z); c0.w = fmaf(hk, w0.w, c0.w);
            c1.x = fmaf(hk, w1.x, c1.x); c1.y = fmaf(hk, w1.y, c1.y);
            c1.z = fmaf(hk, w1.z, c1.z); c1.w = fmaf(hk, w1.w, c1.w);
            c2.x = fmaf(hk, w2.x, c2.x); c2.y = fmaf(hk, w2.y, c2.y);
            c2.z = fmaf(hk, w2.z, c2.z); c2.w = fmaf(hk, w2.w, c2.w);
            c3.x = fmaf(hk, w3.x, c3.x); c3.y = fmaf(hk, w3.y, c3.y);
            c3.z = fmaf(hk, w3.z, c3.z); c3.w = fmaf(hk, w3.w, c3.w);
        }
        // epilogue for this slice's 16 dims:
        // hn[d] = ge*relu(ti + (ge>=0 ? max_m tj : min_m tj) + be) + bte
        {
            const float4* gev  = (const float4*)(ge  + s * 16);
            const float4* bev  = (const float4*)(be  + s * 16);
            const float4* btev = (const float4*)(bte + s * 16);
            float acc[16] = {c0.x,c0.y,c0.z,c0.w, c1.x,c1.y,c1.z,c1.w,
                             c2.x,c2.y,c2.z,c2.w, c3.x,c3.y,c3.z,c3.w};
#pragma unroll
            for (int i4 = 0; i4 < 4; ++i4) {
                float4 gv  = gev[i4];
                float4 be4 = bev[i4];
                float4 bt4 = btev[i4];
                int d0 = s * 16 + 4 * i4;   // LDS broadcast reads (wave-uniform addr)
                float s0 = acc[4*i4+0] + (gv.x >= 0.f ? redmax[d0+0] : redmin[d0+0]) + be4.x;
                float s1 = acc[4*i4+1] + (gv.y >= 0.f ? redmax[d0+1] : redmin[d0+1]) + be4.y;
                float s2 = acc[4*i4+2] + (gv.z >= 0.f ? redmax[d0+2] : redmin[d0+2]) + be4.z;
                float s3 = acc[4*i4+3] + (gv.w >= 0.f ? redmax[d0+3] : redmin[d0+3]) + be4.w;
                hn[4*i4+0] = gv.x * fmaxf(s0, 0.f) + bt4.x;
                hn[4*i4+1] = gv.y * fmaxf(s1, 0.f) + bt4.y;
                hn[4*i4+2] = gv.z * fmaxf(s2, 0.f) + bt4.z;
                hn[4*i4+3] = gv.w * fmaxf(s3, 0.f) + bt4.w;
            }
        }
        // NOTE: safe to write T after return — all threads passed the sync
        // following the reduction reads of T.
    };

    float hn[16];

    // ---------------- edge conv 1 + full-h round trip through LDS ----------------
    edge_conv(We1, be1, ge1, bte1, hn);
    {
        float* Tw = T + n * 65 + s * 16;
#pragma unroll
        for (int i = 0; i < 16; ++i) Tw[i] = hn[i];
    }
    __syncthreads();
#pragma unroll
    for (int k = 0; k < DD; ++k) h[k] = T[n * 65 + k];
    // (next edge_conv's first sync protects T before its overwrite)

    // ---------------- edge conv 2 ----------------
    edge_conv(We2, be2, ge2, bte2, hn);

    // ---------------- global pooling: mean & max over nodes ----------------
    {
        float* Tw = T + n * 65 + s * 16;
#pragma unroll
        for (int i = 0; i < 16; ++i) Tw[i] = hn[i];
    }
    __syncthreads();
    {
        float sm = 0.f, mx = -FMAXV;
#pragma unroll
        for (int m = 0; m < 16; ++m) {
            float v = T[(rg * 16 + m) * 65 + rd];
            sm += v;
            mx = fmaxf(mx, v);
        }
        PA[rg * 64 + rd] = sm;
        PB[rg * 64 + rd] = mx;
    }
    __syncthreads();
    if (t < 64) {
        float asum = PA[t], amax = PB[t];
#pragma unroll
        for (int q = 1; q < 16; ++q) {
            asum += PA[q * 64 + t];
            amax = fmaxf(amax, PB[q * 64 + t]);
        }
        xg[t]      = asum * (1.f / 256.f);
        xg[64 + t] = amax;
    }
    __syncthreads();

    // ---------------- head MLP, layer 1 parallel over 1024 threads ----------------
    {
        float p = 0.f;
#pragma unroll
        for (int j = 0; j < 8; ++j) {
            int k = rg * 8 + j;
            p = fmaf(xg[k], Wg1[k * 64 + rd], p);
        }
        PA[rg * 64 + rd] = p;
    }
    __syncthreads();
    if (t < 64) {
        float a = bg1[t];
#pragma unroll
        for (int q = 0; q < 16; ++q) a += PA[q * 64 + t];
        hid[t] = fmaxf(a, 0.f);
    }
    __syncthreads();
    if (t < 2) {
        float o = bg2[t];
#pragma unroll
        for (int j = 0; j < 64; ++j) o = fmaf(hid[j], Wg2[j * 2 + t], o);
        out[b * 2 + t] = o;
    }
}

extern "C" void kernel_launch(void* const* d_in, const int* in_sizes, int n_in,
                              void* d_out, int out_size, void* d_ws, size_t ws_size,
                              hipStream_t stream) {
    const float* x     = (const float*)d_in[0];
    const float* W1    = (const float*)d_in[1];
    const float* b1    = (const float*)d_in[2];
    const float* g1    = (const float*)d_in[3];
    const float* beta1 = (const float*)d_in[4];
    const float* We1   = (const float*)d_in[5];
    const float* be1   = (const float*)d_in[6];
    const float* ge1   = (const float*)d_in[7];
    const float* bte1  = (const float*)d_in[8];
    const float* We2   = (const float*)d_in[9];
    const float* be2   = (const float*)d_in[10];
    const float* ge2   = (const float*)d_in[11];
    const float* bte2  = (const float*)d_in[12];
    const float* Wg1   = (const float*)d_in[13];
    const float* bg1   = (const float*)d_in[14];
    const float* Wg2   = (const float*)d_in[15];
    const float* bg2   = (const float*)d_in[16];

    pnet_kernel<<<dim3(NB), dim3(1024), 0, stream>>>(
        x, W1, b1, g1, beta1, We1, be1, ge1, bte1,
        We2, be2, ge2, bte2, Wg1, bg1, Wg2, bg2, (float*)d_out);
}

// Round 5
// 171.637 us; speedup vs baseline: 1.5772x; 1.5772x over previous
//
#include <hip/hip_runtime.h>

#define NB 32
#define NN 256
#define DD 64
#define FMAXV 3.402823466e+38f

// R5: h NEVER lives in per-thread registers (R1/R3/R4 all died on h[64]
// blowing the VGPR budget: R1 HBM spill, R3 AGPR-spill latency, R4 scratch
// spill at the 1024-thread 128-VGPR cap). h lives in LDS H[256 x 65]
// (stride 65 -> 2-way bank alias only, free). Thread (n = t&255, s = t>>8)
// computes 16 output dims; k-loop reads h via one ds_read_b32 + 32 FMAs
// (ti+tj fused -> h dies after one pass, tj staging reuses H). Live regs
// ~100 < 128 cap -> no spill. Weight loads wave-uniform -> scalar.
__global__ __launch_bounds__(1024, 1) void pnet_kernel(
    const float* __restrict__ x,
    const float* __restrict__ W1,  const float* __restrict__ b1,
    const float* __restrict__ g1,  const float* __restrict__ beta1,
    const float* __restrict__ We1, const float* __restrict__ be1,
    const float* __restrict__ ge1, const float* __restrict__ bte1,
    const float* __restrict__ We2, const float* __restrict__ be2,
    const float* __restrict__ ge2, const float* __restrict__ bte2,
    const float* __restrict__ Wg1, const float* __restrict__ bg1,
    const float* __restrict__ Wg2, const float* __restrict__ bg2,
    float* __restrict__ out)
{
    __shared__ float H[NN * 65];      // 66.6 KB: h (and, transiently, tj staging)
    __shared__ float PA[16 * 64];     // per-wave-group partials
    __shared__ float PB[16 * 64];
    __shared__ float redmax[DD], redmin[DD];
    __shared__ float xg[2 * DD];
    __shared__ float hid[DD];

    const int t  = threadIdx.x;
    const int b  = blockIdx.x;
    const int n  = t & 255;                                  // node
    const int s  = __builtin_amdgcn_readfirstlane(t >> 8);   // dim slice (SGPR, wave-uniform)
    const int rd = t & 63;                                   // reduce: dim = lane
    const int rg = t >> 6;                                   // reduce: node group = wave id (uniform)

    // ---------------- layer 1: H[n, s*16..s*16+16] = bn(relu(x @ W1 + b1)) ----------------
    {
        float4 xv = *(const float4*)(x + ((size_t)b * NN + n) * 4);
#pragma unroll
        for (int i4 = 0; i4 < 4; ++i4) {
            float4 a  = ((const float4*)(b1 + s * 16))[i4];
            float4 w0 = ((const float4*)(W1 + 0 * DD + s * 16))[i4];
            float4 w1 = ((const float4*)(W1 + 1 * DD + s * 16))[i4];
            float4 w2 = ((const float4*)(W1 + 2 * DD + s * 16))[i4];
            float4 w3 = ((const float4*)(W1 + 3 * DD + s * 16))[i4];
            a.x += xv.x * w0.x + xv.y * w1.x + xv.z * w2.x + xv.w * w3.x;
            a.y += xv.x * w0.y + xv.y * w1.y + xv.z * w2.y + xv.w * w3.y;
            a.z += xv.x * w0.z + xv.y * w1.z + xv.z * w2.z + xv.w * w3.z;
            a.w += xv.x * w0.w + xv.y * w1.w + xv.z * w2.w + xv.w * w3.w;
            float4 g  = ((const float4*)(g1 + s * 16))[i4];
            float4 bt = ((const float4*)(beta1 + s * 16))[i4];
            float* Hw = H + n * 65 + s * 16 + 4 * i4;
            Hw[0] = g.x * fmaxf(a.x, 0.f) + bt.x;
            Hw[1] = g.y * fmaxf(a.y, 0.f) + bt.y;
            Hw[2] = g.z * fmaxf(a.z, 0.f) + bt.z;
            Hw[3] = g.w * fmaxf(a.w, 0.f) + bt.w;
        }
    }
    __syncthreads();

    // ---------------- edge conv (x2): reads h from H, writes h_new to H ----------------
    auto edge_conv = [&](const float* __restrict__ We, const float* __restrict__ be,
                         const float* __restrict__ ge, const float* __restrict__ bte) {
        float ti[16], tj[16];
#pragma unroll
        for (int i = 0; i < 16; ++i) { ti[i] = 0.f; tj[i] = 0.f; }

        // fused matvec: ti (rows 0..63) and tj (rows 64..127), h read once per k
#pragma unroll
        for (int k = 0; k < DD; ++k) {
            const float hk = H[n * 65 + k];
            const float4* wi = (const float4*)(We + k * DD + s * 16);
            const float4* wj = (const float4*)(We + (DD + k) * DD + s * 16);
#pragma unroll
            for (int i4 = 0; i4 < 4; ++i4) {
                float4 a = wi[i4];
                float4 c = wj[i4];
                ti[4*i4+0] = fmaf(hk, a.x, ti[4*i4+0]);
                ti[4*i4+1] = fmaf(hk, a.y, ti[4*i4+1]);
                ti[4*i4+2] = fmaf(hk, a.z, ti[4*i4+2]);
                ti[4*i4+3] = fmaf(hk, a.w, ti[4*i4+3]);
                tj[4*i4+0] = fmaf(hk, c.x, tj[4*i4+0]);
                tj[4*i4+1] = fmaf(hk, c.y, tj[4*i4+1]);
                tj[4*i4+2] = fmaf(hk, c.z, tj[4*i4+2]);
                tj[4*i4+3] = fmaf(hk, c.w, tj[4*i4+3]);
            }
        }
        __syncthreads();              // everyone done reading h -> H reusable

        // stage tj into H (h is dead)
        {
            float* Hw = H + n * 65 + s * 16;
#pragma unroll
            for (int i = 0; i < 16; ++i) Hw[i] = tj[i];
        }
        __syncthreads();

        // partial max/min over this wave-group's 16 nodes, per dim rd
        {
            float mx = -FMAXV, mn = FMAXV;
#pragma unroll
            for (int m = 0; m < 16; ++m) {
                float v = H[(rg * 16 + m) * 65 + rd];
                mx = fmaxf(mx, v);
                mn = fminf(mn, v);
            }
            PA[rg * 64 + rd] = mx;
            PB[rg * 64 + rd] = mn;
        }
        __syncthreads();
        if (t < 64) {
            float amax = PA[t], amin = PB[t];
#pragma unroll
            for (int q = 1; q < 16; ++q) {
                amax = fmaxf(amax, PA[q * 64 + t]);
                amin = fminf(amin, PB[q * 64 + t]);
            }
            redmax[t] = amax;
            redmin[t] = amin;
        }
        __syncthreads();

        // epilogue: h_new = ge*relu(ti + (ge>=0 ? max_m tj : min_m tj) + be) + bte
        // (tj staging in H is dead: its readers finished before previous sync)
#pragma unroll
        for (int i4 = 0; i4 < 4; ++i4) {
            float4 gv  = ((const float4*)(ge  + s * 16))[i4];
            float4 be4 = ((const float4*)(be  + s * 16))[i4];
            float4 bt4 = ((const float4*)(bte + s * 16))[i4];
            const int d0 = s * 16 + 4 * i4;
            float s0 = ti[4*i4+0] + (gv.x >= 0.f ? redmax[d0+0] : redmin[d0+0]) + be4.x;
            float s1 = ti[4*i4+1] + (gv.y >= 0.f ? redmax[d0+1] : redmin[d0+1]) + be4.y;
            float s2 = ti[4*i4+2] + (gv.z >= 0.f ? redmax[d0+2] : redmin[d0+2]) + be4.z;
            float s3 = ti[4*i4+3] + (gv.w >= 0.f ? redmax[d0+3] : redmin[d0+3]) + be4.w;
            float* Hw = H + n * 65 + d0;
            Hw[0] = gv.x * fmaxf(s0, 0.f) + bt4.x;
            Hw[1] = gv.y * fmaxf(s1, 0.f) + bt4.y;
            Hw[2] = gv.z * fmaxf(s2, 0.f) + bt4.z;
            Hw[3] = gv.w * fmaxf(s3, 0.f) + bt4.w;
        }
        __syncthreads();              // h_new complete before next phase reads H
    };

    edge_conv(We1, be1, ge1, bte1);
    edge_conv(We2, be2, ge2, bte2);

    // ---------------- global pooling: mean & max over nodes ----------------
    {
        float sm = 0.f, mx = -FMAXV;
#pragma unroll
        for (int m = 0; m < 16; ++m) {
            float v = H[(rg * 16 + m) * 65 + rd];
            sm += v;
            mx = fmaxf(mx, v);
        }
        PA[rg * 64 + rd] = sm;
        PB[rg * 64 + rd] = mx;
    }
    __syncthreads();
    if (t < 64) {
        float asum = PA[t], amax = PB[t];
#pragma unroll
        for (int q = 1; q < 16; ++q) {
            asum += PA[q * 64 + t];
            amax = fmaxf(amax, PB[q * 64 + t]);
        }
        xg[t]      = asum * (1.f / 256.f);
        xg[64 + t] = amax;
    }
    __syncthreads();

    // ---------------- head MLP ----------------
    {
        float p = 0.f;
#pragma unroll
        for (int j = 0; j < 8; ++j) {
            int k = rg * 8 + j;
            p = fmaf(xg[k], Wg1[k * DD + rd], p);
        }
        PA[rg * 64 + rd] = p;
    }
    __syncthreads();
    if (t < 64) {
        float a = bg1[t];
#pragma unroll
        for (int q = 0; q < 16; ++q) a += PA[q * 64 + t];
        hid[t] = fmaxf(a, 0.f);
    }
    __syncthreads();
    if (t < 2) {
        float o = bg2[t];
#pragma unroll
        for (int j = 0; j < DD; ++j) o = fmaf(hid[j], Wg2[j * 2 + t], o);
        out[b * 2 + t] = o;
    }
}

extern "C" void kernel_launch(void* const* d_in, const int* in_sizes, int n_in,
                              void* d_out, int out_size, void* d_ws, size_t ws_size,
                              hipStream_t stream) {
    const float* x     = (const float*)d_in[0];
    const float* W1    = (const float*)d_in[1];
    const float* b1    = (const float*)d_in[2];
    const float* g1    = (const float*)d_in[3];
    const float* beta1 = (const float*)d_in[4];
    const float* We1   = (const float*)d_in[5];
    const float* be1   = (const float*)d_in[6];
    const float* ge1   = (const float*)d_in[7];
    const float* bte1  = (const float*)d_in[8];
    const float* We2   = (const float*)d_in[9];
    const float* be2   = (const float*)d_in[10];
    const float* ge2   = (const float*)d_in[11];
    const float* bte2  = (const float*)d_in[12];
    const float* Wg1   = (const float*)d_in[13];
    const float* bg1   = (const float*)d_in[14];
    const float* Wg2   = (const float*)d_in[15];
    const float* bg2   = (const float*)d_in[16];

    pnet_kernel<<<dim3(NB), dim3(1024), 0, stream>>>(
        x, W1, b1, g1, beta1, We1, be1, ge1, bte1,
        We2, be2, ge2, bte2, Wg1, bg1, Wg2, bg2, (float*)d_out);
}

// Round 6
// 121.398 us; speedup vs baseline: 2.2300x; 1.4138x over previous
//
#include <hip/hip_runtime.h>

#define NB 32
#define NN 256
#define DD 64
#define GG 4            // node-groups per batch
#define NPB 64          // nodes per block
#define FMAXV 3.402823466e+38f

// R6: multi-kernel pipeline to use 128 CUs instead of 32 (R5 was VALU-bound
// at ~47% on 32 occupied CUs; 224 CUs idle). Grid = NB*GG = 128 blocks of
// 512 threads: lane = node (64/block), wave = 8-dim slice (wave-uniform ->
// weight reads become s_load; k-loop is 1 ds_read_b32 + 16 FMA). Node
// reductions = 64-lane shfl_xor butterflies. Cross-block (per-batch) tj
// max/min via ws partials combined in the NEXT kernel (stream order
// guarantees visibility). ti round-trips through ws (in-place safe: each
// element read and written by the same thread).
//
// ws layout (floats):
//   TI    @ 0        NB*NN*DD = 524288
//   PMAX1 @ 524288   NB*GG*DD = 8192
//   PMIN1 @ 532480   8192
//   PMAX2 @ 540672   8192
//   PMIN2 @ 548864   8192
//   PSUM  @ 557056   8192
//   PMXP  @ 565248   8192   (total 573440 floats = 2.29 MB)

__global__ __launch_bounds__(512) void k_conv1(
    const float* __restrict__ x,
    const float* __restrict__ W1,  const float* __restrict__ b1,
    const float* __restrict__ g1,  const float* __restrict__ beta1,
    const float* __restrict__ We1,
    float* __restrict__ TI, float* __restrict__ PMAX, float* __restrict__ PMIN)
{
    __shared__ float Hs[NPB * 65];   // 64 nodes x 64 dims, stride 65 (2-way alias only)
    const int b  = blockIdx.x >> 2;
    const int g  = blockIdx.x & 3;
    const int l  = threadIdx.x & 63;                                // node lane
    const int w  = __builtin_amdgcn_readfirstlane(threadIdx.x >> 6); // wave 0..7 (SGPR)
    const int n  = g * NPB + l;
    const int d0 = w * 8;                                           // wave's dim slice

    // ---- layer 1: h[n, d0..d0+8] = bn(relu(x @ W1 + b1)) ----
    {
        float4 xv = *(const float4*)(x + ((size_t)b * NN + n) * 4);
        float a[8];
#pragma unroll
        for (int j = 0; j < 8; ++j) a[j] = b1[d0 + j];
#pragma unroll
        for (int j = 0; j < 8; ++j) a[j] = fmaf(xv.x, W1[0 * DD + d0 + j], a[j]);
#pragma unroll
        for (int j = 0; j < 8; ++j) a[j] = fmaf(xv.y, W1[1 * DD + d0 + j], a[j]);
#pragma unroll
        for (int j = 0; j < 8; ++j) a[j] = fmaf(xv.z, W1[2 * DD + d0 + j], a[j]);
#pragma unroll
        for (int j = 0; j < 8; ++j) a[j] = fmaf(xv.w, W1[3 * DD + d0 + j], a[j]);
#pragma unroll
        for (int j = 0; j < 8; ++j)
            Hs[l * 65 + d0 + j] = g1[d0 + j] * fmaxf(a[j], 0.f) + beta1[d0 + j];
    }
    __syncthreads();

    // ---- conv1 matvec: ti/tj[d0..d0+8] for node n; weights via s_load ----
    float ti[8], tj[8];
#pragma unroll
    for (int j = 0; j < 8; ++j) { ti[j] = 0.f; tj[j] = 0.f; }
#pragma unroll
    for (int k = 0; k < DD; ++k) {
        const float hk = Hs[l * 65 + k];
        const float* wi = We1 + k * DD + d0;          // wave-uniform address
        const float* wj = We1 + (DD + k) * DD + d0;   // wave-uniform address
#pragma unroll
        for (int j = 0; j < 8; ++j) {
            ti[j] = fmaf(hk, wi[j], ti[j]);
            tj[j] = fmaf(hk, wj[j], tj[j]);
        }
    }
    // store ti -> ws
    {
        float* o = TI + ((size_t)(b * NN + n)) * DD + d0;
        *(float4*)(o)     = make_float4(ti[0], ti[1], ti[2], ti[3]);
        *(float4*)(o + 4) = make_float4(ti[4], ti[5], ti[6], ti[7]);
    }
    // butterfly max/min of tj over the 64 nodes (lanes)
    float mx[8], mn[8];
#pragma unroll
    for (int j = 0; j < 8; ++j) { mx[j] = tj[j]; mn[j] = tj[j]; }
#pragma unroll
    for (int m = 1; m < 64; m <<= 1) {
#pragma unroll
        for (int j = 0; j < 8; ++j) {
            mx[j] = fmaxf(mx[j], __shfl_xor(mx[j], m, 64));
            mn[j] = fminf(mn[j], __shfl_xor(mn[j], m, 64));
        }
    }
    float smx = mx[0], smn = mn[0];
#pragma unroll
    for (int j = 1; j < 8; ++j) {
        smx = (l == j) ? mx[j] : smx;
        smn = (l == j) ? mn[j] : smn;
    }
    if (l < 8) {
        PMAX[(b * GG + g) * DD + d0 + l] = smx;
        PMIN[(b * GG + g) * DD + d0 + l] = smn;
    }
}

// epilogue of previous conv (using its partial reductions) + next conv matvec
__global__ __launch_bounds__(512) void k_conv2(
    const float* __restrict__ PMAXin, const float* __restrict__ PMINin,
    const float* __restrict__ beP, const float* __restrict__ geP,
    const float* __restrict__ bteP,
    const float* __restrict__ We,
    float* __restrict__ TI, float* __restrict__ PMAX, float* __restrict__ PMIN)
{
    __shared__ float Hs[NPB * 65];
    const int b  = blockIdx.x >> 2;
    const int g  = blockIdx.x & 3;
    const int l  = threadIdx.x & 63;
    const int w  = __builtin_amdgcn_readfirstlane(threadIdx.x >> 6);
    const int n  = g * NPB + l;
    const int d0 = w * 8;

    // combine the 4 per-group partials (all-scalar: uniform addrs + uniform compare later)
    float rmax[8], rmin[8];
#pragma unroll
    for (int j = 0; j < 8; ++j) {
        rmax[j] = fmaxf(fmaxf(PMAXin[(b * GG + 0) * DD + d0 + j],
                              PMAXin[(b * GG + 1) * DD + d0 + j]),
                        fmaxf(PMAXin[(b * GG + 2) * DD + d0 + j],
                              PMAXin[(b * GG + 3) * DD + d0 + j]));
        rmin[j] = fminf(fminf(PMINin[(b * GG + 0) * DD + d0 + j],
                              PMINin[(b * GG + 1) * DD + d0 + j]),
                        fminf(PMINin[(b * GG + 2) * DD + d0 + j],
                              PMINin[(b * GG + 3) * DD + d0 + j]));
    }
    // epilogue: h = geP*relu(ti_prev + pick + beP) + bteP  (monotone bn o max)
    {
        const float* tip = TI + ((size_t)(b * NN + n)) * DD + d0;
        float4 t0 = *(const float4*)tip;
        float4 t1 = *(const float4*)(tip + 4);
        float tiv[8] = {t0.x, t0.y, t0.z, t0.w, t1.x, t1.y, t1.z, t1.w};
#pragma unroll
        for (int j = 0; j < 8; ++j) {
            float gv = geP[d0 + j];
            float sv = tiv[j] + (gv >= 0.f ? rmax[j] : rmin[j]) + beP[d0 + j];
            Hs[l * 65 + d0 + j] = gv * fmaxf(sv, 0.f) + bteP[d0 + j];
        }
    }
    __syncthreads();

    // next conv matvec
    float ti[8], tj[8];
#pragma unroll
    for (int j = 0; j < 8; ++j) { ti[j] = 0.f; tj[j] = 0.f; }
#pragma unroll
    for (int k = 0; k < DD; ++k) {
        const float hk = Hs[l * 65 + k];
        const float* wi = We + k * DD + d0;
        const float* wj = We + (DD + k) * DD + d0;
#pragma unroll
        for (int j = 0; j < 8; ++j) {
            ti[j] = fmaf(hk, wi[j], ti[j]);
            tj[j] = fmaf(hk, wj[j], tj[j]);
        }
    }
    {
        float* o = TI + ((size_t)(b * NN + n)) * DD + d0;   // in-place: same thread read it
        *(float4*)(o)     = make_float4(ti[0], ti[1], ti[2], ti[3]);
        *(float4*)(o + 4) = make_float4(ti[4], ti[5], ti[6], ti[7]);
    }
    float mx[8], mn[8];
#pragma unroll
    for (int j = 0; j < 8; ++j) { mx[j] = tj[j]; mn[j] = tj[j]; }
#pragma unroll
    for (int m = 1; m < 64; m <<= 1) {
#pragma unroll
        for (int j = 0; j < 8; ++j) {
            mx[j] = fmaxf(mx[j], __shfl_xor(mx[j], m, 64));
            mn[j] = fminf(mn[j], __shfl_xor(mn[j], m, 64));
        }
    }
    float smx = mx[0], smn = mn[0];
#pragma unroll
    for (int j = 1; j < 8; ++j) {
        smx = (l == j) ? mx[j] : smx;
        smn = (l == j) ? mn[j] : smn;
    }
    if (l < 8) {
        PMAX[(b * GG + g) * DD + d0 + l] = smx;
        PMIN[(b * GG + g) * DD + d0 + l] = smn;
    }
}

// conv2 epilogue + pooling partials (sum & max over this block's 64 nodes)
__global__ __launch_bounds__(512) void k_pool(
    const float* __restrict__ PMAXin, const float* __restrict__ PMINin,
    const float* __restrict__ beP, const float* __restrict__ geP,
    const float* __restrict__ bteP,
    const float* __restrict__ TI,
    float* __restrict__ PSUM, float* __restrict__ PMXP)
{
    const int b  = blockIdx.x >> 2;
    const int g  = blockIdx.x & 3;
    const int l  = threadIdx.x & 63;
    const int w  = __builtin_amdgcn_readfirstlane(threadIdx.x >> 6);
    const int n  = g * NPB + l;
    const int d0 = w * 8;

    float rmax[8], rmin[8];
#pragma unroll
    for (int j = 0; j < 8; ++j) {
        rmax[j] = fmaxf(fmaxf(PMAXin[(b * GG + 0) * DD + d0 + j],
                              PMAXin[(b * GG + 1) * DD + d0 + j]),
                        fmaxf(PMAXin[(b * GG + 2) * DD + d0 + j],
                              PMAXin[(b * GG + 3) * DD + d0 + j]));
        rmin[j] = fminf(fminf(PMINin[(b * GG + 0) * DD + d0 + j],
                              PMINin[(b * GG + 1) * DD + d0 + j]),
                        fminf(PMINin[(b * GG + 2) * DD + d0 + j],
                              PMINin[(b * GG + 3) * DD + d0 + j]));
    }
    float hv[8];
    {
        const float* tip = TI + ((size_t)(b * NN + n)) * DD + d0;
        float4 t0 = *(const float4*)tip;
        float4 t1 = *(const float4*)(tip + 4);
        float tiv[8] = {t0.x, t0.y, t0.z, t0.w, t1.x, t1.y, t1.z, t1.w};
#pragma unroll
        for (int j = 0; j < 8; ++j) {
            float gv = geP[d0 + j];
            float sv = tiv[j] + (gv >= 0.f ? rmax[j] : rmin[j]) + beP[d0 + j];
            hv[j] = gv * fmaxf(sv, 0.f) + bteP[d0 + j];
        }
    }
    // butterfly sum & max over 64 nodes
    float sm[8], mx[8];
#pragma unroll
    for (int j = 0; j < 8; ++j) { sm[j] = hv[j]; mx[j] = hv[j]; }
#pragma unroll
    for (int m = 1; m < 64; m <<= 1) {
#pragma unroll
        for (int j = 0; j < 8; ++j) {
            sm[j] += __shfl_xor(sm[j], m, 64);
            mx[j] = fmaxf(mx[j], __shfl_xor(mx[j], m, 64));
        }
    }
    float ssm = sm[0], smx = mx[0];
#pragma unroll
    for (int j = 1; j < 8; ++j) {
        ssm = (l == j) ? sm[j] : ssm;
        smx = (l == j) ? mx[j] : smx;
    }
    if (l < 8) {
        PSUM[(b * GG + g) * DD + d0 + l] = ssm;
        PMXP[(b * GG + g) * DD + d0 + l] = smx;
    }
}

// pooling finalize + head MLP
__global__ __launch_bounds__(128) void k_head(
    const float* __restrict__ PSUM, const float* __restrict__ PMXP,
    const float* __restrict__ Wg1, const float* __restrict__ bg1,
    const float* __restrict__ Wg2, const float* __restrict__ bg2,
    float* __restrict__ out)
{
    __shared__ float xg[2 * DD];
    __shared__ float hid[DD];
    const int b = blockIdx.x;
    const int t = threadIdx.x;
    if (t < 64) {
        float s = PSUM[(b * GG + 0) * DD + t] + PSUM[(b * GG + 1) * DD + t]
                + PSUM[(b * GG + 2) * DD + t] + PSUM[(b * GG + 3) * DD + t];
        xg[t] = s * (1.f / 256.f);
    } else {
        int d = t - 64;
        xg[64 + d] = fmaxf(fmaxf(PMXP[(b * GG + 0) * DD + d], PMXP[(b * GG + 1) * DD + d]),
                           fmaxf(PMXP[(b * GG + 2) * DD + d], PMXP[(b * GG + 3) * DD + d]));
    }
    __syncthreads();
    if (t < 64) {
        float a = bg1[t];
#pragma unroll
        for (int k = 0; k < 2 * DD; ++k) a = fmaf(xg[k], Wg1[k * DD + t], a);
        hid[t] = fmaxf(a, 0.f);
    }
    __syncthreads();
    if (t < 2) {
        float o = bg2[t];
#pragma unroll
        for (int j = 0; j < DD; ++j) o = fmaf(hid[j], Wg2[j * 2 + t], o);
        out[b * 2 + t] = o;
    }
}

extern "C" void kernel_launch(void* const* d_in, const int* in_sizes, int n_in,
                              void* d_out, int out_size, void* d_ws, size_t ws_size,
                              hipStream_t stream) {
    const float* x     = (const float*)d_in[0];
    const float* W1    = (const float*)d_in[1];
    const float* b1    = (const float*)d_in[2];
    const float* g1    = (const float*)d_in[3];
    const float* beta1 = (const float*)d_in[4];
    const float* We1   = (const float*)d_in[5];
    const float* be1   = (const float*)d_in[6];
    const float* ge1   = (const float*)d_in[7];
    const float* bte1  = (const float*)d_in[8];
    const float* We2   = (const float*)d_in[9];
    const float* be2   = (const float*)d_in[10];
    const float* ge2   = (const float*)d_in[11];
    const float* bte2  = (const float*)d_in[12];
    const float* Wg1   = (const float*)d_in[13];
    const float* bg1   = (const float*)d_in[14];
    const float* Wg2   = (const float*)d_in[15];
    const float* bg2   = (const float*)d_in[16];

    float* ws    = (float*)d_ws;
    float* TI    = ws;
    float* PMAX1 = ws + 524288;
    float* PMIN1 = ws + 532480;
    float* PMAX2 = ws + 540672;
    float* PMIN2 = ws + 548864;
    float* PSUM  = ws + 557056;
    float* PMXP  = ws + 565248;

    k_conv1<<<dim3(NB * GG), dim3(512), 0, stream>>>(
        x, W1, b1, g1, beta1, We1, TI, PMAX1, PMIN1);
    k_conv2<<<dim3(NB * GG), dim3(512), 0, stream>>>(
        PMAX1, PMIN1, be1, ge1, bte1, We2, TI, PMAX2, PMIN2);
    k_pool<<<dim3(NB * GG), dim3(512), 0, stream>>>(
        PMAX2, PMIN2, be2, ge2, bte2, TI, PSUM, PMXP);
    k_head<<<dim3(NB), dim3(128), 0, stream>>>(
        PSUM, PMXP, Wg1, bg1, Wg2, bg2, (float*)d_out);
}